// Round 2
// baseline (446.326 us; speedup 1.0000x reference)
//
#include <hip/hip_runtime.h>

// ---------------------------------------------------------------------------
// GraphAttention fused kernels for MI355X (gfx950).
// Dtype-adaptive: detect_kernel probes whether tensors are bf16 or fp32 and
// writes a flag; every worker kernel is templated on MODE (0=bf16, 1=fp32)
// and early-returns if the flag doesn't match. Internal math: bf16 MFMA with
// fp32 accumulation in both modes.
// Pipeline: memset(ws) -> detect -> prep<0|1> -> stats<0|1> -> main<0|1>
// ---------------------------------------------------------------------------

#define VNODES 10
#define CH 128
#define HEADS 8
#define ROWS_TOTAL 327680      // N*T*VN = 64*512*10
#define G 8                    // batch items per main-kernel block
#define MROWS 80               // G * VNODES rows per block
#define MT 5                   // 16-row m-tiles per block
#define SY 136                 // yTile LDS row stride (elems)
#define SQ 392                 // qkv LDS row stride (elems)

typedef __bf16 bf16x8 __attribute__((ext_vector_type(8)));
typedef float f32x4 __attribute__((ext_vector_type(4)));
typedef unsigned short u16x8 __attribute__((ext_vector_type(8)));
typedef unsigned short u16x4 __attribute__((ext_vector_type(4)));

__device__ __forceinline__ float bf2f(unsigned short u) {
    return __uint_as_float(((unsigned)u) << 16);
}
__device__ __forceinline__ unsigned short f2bf(float f) {
    unsigned u = __float_as_uint(f);
    u += 0x7fffu + ((u >> 16) & 1u);   // round-to-nearest-even
    return (unsigned short)(u >> 16);
}

// ---------------------------------------------------------------------------
// Dtype detector: view first 8192 u16 of x as bf16. Real bf16 N(0,1) data
// maxes ~5; fp32 bits viewed as bf16 give huge exponents / NaN. flag=1 => fp32.
// ---------------------------------------------------------------------------
__global__ __launch_bounds__(256) void detect_kernel(
        const unsigned short* __restrict__ xr, int* __restrict__ flag) {
    __shared__ float red[256];
    int t = threadIdx.x;
    float mx = 0.f;
    for (int i = t; i < 8192; i += 256) {
        float a = fabsf(bf2f(xr[i]));
        if (!(a < 1e9f)) a = 1e9f;     // NaN/inf -> big
        mx = fmaxf(mx, a);
    }
    red[t] = mx;
    __syncthreads();
    for (int s = 128; s > 0; s >>= 1) {
        if (t < s) red[t] = fmaxf(red[t], red[t + s]);
        __syncthreads();
    }
    if (t == 0) *flag = (red[0] > 1000.f) ? 1 : 0;
}

// ---------------------------------------------------------------------------
// Weight prep into MFMA B-fragment order:
// frag[nt][kt][lane][j] = W[kt*32 + (lane>>4)*8 + j][nt*16 + (lane&15)]
// ---------------------------------------------------------------------------
template<int MODE>
__global__ __launch_bounds__(256) void prep_kernel(
        const void* __restrict__ wqkv_, const void* __restrict__ wout_,
        const int* __restrict__ flag,
        unsigned short* __restrict__ fq, unsigned short* __restrict__ fo) {
    if (*flag != MODE) return;
    const unsigned short* wq16 = (const unsigned short*)wqkv_;
    const float*          wq32 = (const float*)wqkv_;
    const unsigned short* wo16 = (const unsigned short*)wout_;
    const float*          wo32 = (const float*)wout_;
    int tid = blockIdx.x * 256 + threadIdx.x;
    if (tid < 24 * 4 * 64) {                 // w_qkv: nt 0..23
        int l = tid & 63;
        int kt = (tid >> 6) & 3;
        int nt = tid >> 8;
        int quad = l >> 4, n = l & 15;
#pragma unroll
        for (int j = 0; j < 8; ++j) {
            int idx = (kt * 32 + quad * 8 + j) * 384 + nt * 16 + n;
            fq[tid * 8 + j] = MODE ? f2bf(wq32[idx]) : wq16[idx];
        }
    } else if (tid < 24 * 4 * 64 + 8 * 4 * 64) {   // w_out: nt 0..7
        int u = tid - 24 * 4 * 64;
        int l = u & 63;
        int kt = (u >> 6) & 3;
        int nt = u >> 8;
        int quad = l >> 4, n = l & 15;
#pragma unroll
        for (int j = 0; j < 8; ++j) {
            int idx = (kt * 32 + quad * 8 + j) * 128 + nt * 16 + n;
            fo[u * 8 + j] = MODE ? f2bf(wo32[idx]) : wo16[idx];
        }
    }
}

// ---------------------------------------------------------------------------
// BN statistics: per-channel sum / sum-of-squares over all rows.
// 1024 blocks x 256 threads, 320 rows per block.
// ---------------------------------------------------------------------------
template<int MODE>
__global__ __launch_bounds__(256) void stats_kernel(
        const void* __restrict__ x_, const int* __restrict__ flag,
        float* __restrict__ ws_sum, float* __restrict__ ws_sq) {
    if (*flag != MODE) return;
    int t = threadIdx.x;
    if (MODE == 0) {
        const unsigned short* x = (const unsigned short*)x_;
        __shared__ float lsum[16][128];
        __shared__ float lsq[16][128];
        int slot = t >> 4, g = t & 15;
        float s[8], q[8];
#pragma unroll
        for (int k = 0; k < 8; ++k) { s[k] = 0.f; q[k] = 0.f; }
        size_t base_row = (size_t)blockIdx.x * 320;
        for (int p = 0; p < 20; ++p) {
            size_t row = base_row + p * 16 + slot;
            u16x8 v = *(const u16x8*)(x + row * CH + g * 8);
#pragma unroll
            for (int k = 0; k < 8; ++k) {
                float f = bf2f(v[k]);
                s[k] += f;
                q[k] = fmaf(f, f, q[k]);
            }
        }
#pragma unroll
        for (int k = 0; k < 8; ++k) { lsum[slot][g * 8 + k] = s[k]; lsq[slot][g * 8 + k] = q[k]; }
        __syncthreads();
        if (t < 128) {
            float ts = 0.f, tq = 0.f;
#pragma unroll
            for (int sl = 0; sl < 16; ++sl) { ts += lsum[sl][t]; tq += lsq[sl][t]; }
            atomicAdd(&ws_sum[t], ts);
            atomicAdd(&ws_sq[t], tq);
        }
    } else {
        const float* x = (const float*)x_;
        __shared__ float lsum[8][128];
        __shared__ float lsq[8][128];
        int slot = t >> 5, g = t & 31;
        float s[4], q[4];
#pragma unroll
        for (int k = 0; k < 4; ++k) { s[k] = 0.f; q[k] = 0.f; }
        size_t base_row = (size_t)blockIdx.x * 320;
        for (int p = 0; p < 40; ++p) {
            size_t row = base_row + p * 8 + slot;
            f32x4 v = *(const f32x4*)(x + row * CH + g * 4);
#pragma unroll
            for (int k = 0; k < 4; ++k) {
                s[k] += v[k];
                q[k] = fmaf(v[k], v[k], q[k]);
            }
        }
#pragma unroll
        for (int k = 0; k < 4; ++k) { lsum[slot][g * 4 + k] = s[k]; lsq[slot][g * 4 + k] = q[k]; }
        __syncthreads();
        if (t < 128) {
            float ts = 0.f, tq = 0.f;
#pragma unroll
            for (int sl = 0; sl < 8; ++sl) { ts += lsum[sl][t]; tq += lsq[sl][t]; }
            atomicAdd(&ws_sum[t], ts);
            atomicAdd(&ws_sq[t], tq);
        }
    }
}

// ---------------------------------------------------------------------------
// Main fused kernel: 512 threads (8 waves), 4096 blocks, 80 rows each.
// ---------------------------------------------------------------------------
template<int MODE>
__global__ __launch_bounds__(512) void main_kernel(
        const void* __restrict__ x_,
        const void* __restrict__ gamma_,
        const void* __restrict__ beta_,
        const void* __restrict__ mask_,
        const int* __restrict__ flag,
        const float* __restrict__ ws_stats,
        const unsigned short* __restrict__ wqkv_f,
        const unsigned short* __restrict__ wout_f,
        const void* __restrict__ b_out_,
        void* __restrict__ out_) {
    if (*flag != MODE) return;
    __shared__ __align__(16) unsigned short yT[MROWS * SY];     // 21,760 B
    __shared__ __align__(16) unsigned short qkvT[MROWS * SQ];   // 62,720 B
    __shared__ float scale_s[CH], shift_s[CH], bout_s[CH], mask_s[VNODES * VNODES];

    int tid = threadIdx.x;
    int lane = tid & 63, w = tid >> 6;
    size_t row0 = (size_t)blockIdx.x * MROWS;

    // ---- phase 0: BN scale/shift, bias, mask into LDS ----
    if (tid < CH) {
        float sum = ws_stats[tid], sq = ws_stats[128 + tid];
        float mean = sum * (1.0f / ROWS_TOTAL);
        float var = sq * (1.0f / ROWS_TOTAL) - mean * mean;
        float inv = rsqrtf(var + 1e-5f);
        float gm = MODE ? ((const float*)gamma_)[tid] : bf2f(((const unsigned short*)gamma_)[tid]);
        float bt = MODE ? ((const float*)beta_)[tid]  : bf2f(((const unsigned short*)beta_)[tid]);
        float sc = gm * inv;
        scale_s[tid] = sc;
        shift_s[tid] = bt - mean * sc;
    } else if (tid < 256) {
        int c = tid - 128;
        bout_s[c] = MODE ? ((const float*)b_out_)[c] : bf2f(((const unsigned short*)b_out_)[c]);
    } else if (tid < 256 + VNODES * VNODES) {
        int c = tid - 256;
        mask_s[c] = MODE ? ((const float*)mask_)[c] : bf2f(((const unsigned short*)mask_)[c]);
    }
    __syncthreads();

    // ---- phase 1: y = x*scale + shift -> yT (bf16) ----
    if (MODE == 0) {
        const unsigned short* x = (const unsigned short*)x_;
        int rloc = tid >> 4, g = tid & 15;
        for (int p = 0; p < 3; ++p) {
            int r = p * 32 + rloc;
            if (r < MROWS) {
                u16x8 v = *(const u16x8*)(x + (row0 + r) * CH + g * 8);
                u16x8 o;
#pragma unroll
                for (int k = 0; k < 8; ++k) {
                    int c = g * 8 + k;
                    o[k] = f2bf(fmaf(bf2f(v[k]), scale_s[c], shift_s[c]));
                }
                *(u16x8*)(yT + r * SY + g * 8) = o;
            }
        }
    } else {
        const float* x = (const float*)x_;
        int rloc = tid >> 5, g = tid & 31;
        for (int p = 0; p < 5; ++p) {
            int r = p * 16 + rloc;
            f32x4 v = *(const f32x4*)(x + (row0 + r) * CH + g * 4);
            u16x4 o;
#pragma unroll
            for (int k = 0; k < 4; ++k) {
                int c = g * 4 + k;
                o[k] = f2bf(fmaf(v[k], scale_s[c], shift_s[c]));
            }
            *(u16x4*)(yT + r * SY + g * 4) = o;
        }
    }
    __syncthreads();

    // ---- phase 2: qkv = y @ w_qkv via MFMA; wave w owns n-tiles {w, w+8, w+16} ----
    {
        bf16x8 bf[3][4];
#pragma unroll
        for (int ni = 0; ni < 3; ++ni) {
            int nt = w + ni * 8;
#pragma unroll
            for (int kt = 0; kt < 4; ++kt)
                bf[ni][kt] = *(const bf16x8*)(wqkv_f + ((nt * 4 + kt) * 64 + lane) * 8);
        }
        int l15 = lane & 15, quad = lane >> 4;
        for (int mt = 0; mt < MT; ++mt) {
            bf16x8 a[4];
#pragma unroll
            for (int kt = 0; kt < 4; ++kt)
                a[kt] = *(const bf16x8*)(yT + (mt * 16 + l15) * SY + kt * 32 + quad * 8);
#pragma unroll
            for (int ni = 0; ni < 3; ++ni) {
                f32x4 acc = {0.f, 0.f, 0.f, 0.f};
#pragma unroll
                for (int kt = 0; kt < 4; ++kt)
                    acc = __builtin_amdgcn_mfma_f32_16x16x32_bf16(a[kt], bf[ni][kt], acc, 0, 0, 0);
                int col = (w + ni * 8) * 16 + l15;   // C/D: col = lane&15
#pragma unroll
                for (int i = 0; i < 4; ++i) {
                    int rr = mt * 16 + quad * 4 + i; // C/D: row = quad*4 + reg
                    qkvT[rr * SQ + col] = f2bf(acc[i]);
                }
            }
        }
    }
    __syncthreads();

    // ---- phase 2b: masked attention (fp32 vector); 640 tasks over 512 threads ----
    for (int task = tid; task < G * HEADS * VNODES; task += 512) {
        int h = task / (G * VNODES);
        int rem = task - h * (G * VNODES);
        int b = rem / VNODES;
        int i = rem - b * VNODES;
        int rowi = b * VNODES + i;
        const unsigned short* qp = qkvT + rowi * SQ + h * 16;
        float qv[16];
#pragma unroll
        for (int d2 = 0; d2 < 8; ++d2) {
            unsigned wd = *(const unsigned*)(qp + d2 * 2);
            qv[d2 * 2]     = __uint_as_float(wd << 16);
            qv[d2 * 2 + 1] = __uint_as_float(wd & 0xffff0000u);
        }
        float p[VNODES];
        float mx = -1e30f;
#pragma unroll
        for (int j = 0; j < VNODES; ++j) {
            const unsigned short* kp = qkvT + (b * VNODES + j) * SQ + 128 + h * 16;
            float dot = 0.f;
#pragma unroll
            for (int d2 = 0; d2 < 8; ++d2) {
                unsigned wd = *(const unsigned*)(kp + d2 * 2);
                dot = fmaf(qv[d2 * 2], __uint_as_float(wd << 16), dot);
                dot = fmaf(qv[d2 * 2 + 1], __uint_as_float(wd & 0xffff0000u), dot);
            }
            // logits = (q.k * scale) * mask; softmax over ALL 10 (masked -> logit 0)
            p[j] = dot * 0.25f * mask_s[i * VNODES + j];
            mx = fmaxf(mx, p[j]);
        }
        float s = 0.f;
#pragma unroll
        for (int j = 0; j < VNODES; ++j) { p[j] = __expf(p[j] - mx); s += p[j]; }
        float inv = 1.0f / s;
#pragma unroll
        for (int d2 = 0; d2 < 8; ++d2) {
            float a0 = 0.f, a1 = 0.f;
#pragma unroll
            for (int j = 0; j < VNODES; ++j) {
                unsigned wd = *(const unsigned*)(qkvT + (b * VNODES + j) * SQ + 256 + h * 16 + d2 * 2);
                a0 = fmaf(p[j], __uint_as_float(wd << 16), a0);
                a1 = fmaf(p[j], __uint_as_float(wd & 0xffff0000u), a1);
            }
            unsigned ow = (unsigned)f2bf(a0 * inv) | ((unsigned)f2bf(a1 * inv) << 16);
            *(unsigned*)(yT + rowi * SY + h * 16 + d2 * 2) = ow;   // yT now = attention output
        }
    }
    __syncthreads();

    // ---- phase 3: final = o @ w_out + b_out via MFMA; wave w owns n-tile w ----
    {
        bf16x8 bfw[4];
#pragma unroll
        for (int kt = 0; kt < 4; ++kt)
            bfw[kt] = *(const bf16x8*)(wout_f + ((w * 4 + kt) * 64 + lane) * 8);
        int l15 = lane & 15, quad = lane >> 4;
        float bias = bout_s[w * 16 + l15];
        for (int mt = 0; mt < MT; ++mt) {
            f32x4 acc = {0.f, 0.f, 0.f, 0.f};
#pragma unroll
            for (int kt = 0; kt < 4; ++kt) {
                bf16x8 a = *(const bf16x8*)(yT + (mt * 16 + l15) * SY + kt * 32 + quad * 8);
                acc = __builtin_amdgcn_mfma_f32_16x16x32_bf16(a, bfw[kt], acc, 0, 0, 0);
            }
            int col = w * 16 + l15;
#pragma unroll
            for (int i = 0; i < 4; ++i) {
                int rr = mt * 16 + quad * 4 + i;
                qkvT[rr * SQ + col] = f2bf(acc[i] + bias);   // qkvT now = final tile
            }
        }
    }
    __syncthreads();

    // ---- phase 4: store ----
    if (MODE == 0) {
        unsigned short* out = (unsigned short*)out_;
        int rloc = tid >> 4, g = tid & 15;
        for (int p = 0; p < 3; ++p) {
            int r = p * 32 + rloc;
            if (r < MROWS) {
                u16x8 v = *(const u16x8*)(qkvT + r * SQ + g * 8);
                *(u16x8*)(out + (row0 + r) * CH + g * 8) = v;
            }
        }
    } else {
        float* out = (float*)out_;
        int rloc = tid >> 5, g = tid & 31;
        for (int p = 0; p < 5; ++p) {
            int r = p * 16 + rloc;
            u16x4 v = *(const u16x4*)(qkvT + r * SQ + g * 4);
            f32x4 o;
#pragma unroll
            for (int k = 0; k < 4; ++k) o[k] = bf2f(v[k]);
            *(f32x4*)(out + (row0 + r) * CH + g * 4) = o;
        }
    }
}

extern "C" void kernel_launch(void* const* d_in, const int* in_sizes, int n_in,
                              void* d_out, int out_size, void* d_ws, size_t ws_size,
                              hipStream_t stream) {
    const void* x     = d_in[0];
    const void* gamma = d_in[1];
    const void* beta  = d_in[2];
    const void* wqkv  = d_in[3];
    const void* wout  = d_in[4];
    const void* bout  = d_in[5];
    const void* maskp = d_in[6];

    char* ws = (char*)d_ws;
    float* ws_stats = (float*)ws;                              // 256 f32 (sum | sumsq)
    int* flag = (int*)(ws + 1024);                             // dtype flag
    unsigned short* fq = (unsigned short*)(ws + 2048);         // 49152 bf16 qkv frags
    unsigned short* fo = (unsigned short*)(ws + 2048 + 98304); // 16384 bf16 out frags

    hipMemsetAsync(ws, 0, 2048, stream);
    detect_kernel<<<1, 256, 0, stream>>>((const unsigned short*)x, flag);
    prep_kernel<0><<<32, 256, 0, stream>>>(wqkv, wout, flag, fq, fo);
    prep_kernel<1><<<32, 256, 0, stream>>>(wqkv, wout, flag, fq, fo);
    stats_kernel<0><<<1024, 256, 0, stream>>>(x, flag, ws_stats, ws_stats + 128);
    stats_kernel<1><<<1024, 256, 0, stream>>>(x, flag, ws_stats, ws_stats + 128);
    main_kernel<0><<<4096, 512, 0, stream>>>(x, gamma, beta, maskp, flag, ws_stats, fq, fo, bout, d_out);
    main_kernel<1><<<4096, 512, 0, stream>>>(x, gamma, beta, maskp, flag, ws_stats, fq, fo, bout, d_out);
}

// Round 3
// 416.957 us; speedup vs baseline: 1.0704x; 1.0704x over previous
//
#include <hip/hip_runtime.h>

// ---------------------------------------------------------------------------
// GraphAttention fused kernels for MI355X (gfx950). fp32 I/O (confirmed R2).
// Pipeline: memset(stats) -> stats -> prep(BN-folded weight frags + qkv bias)
//           -> main (x->bf16, QKV mfma, fp32 attention, out-proj mfma)
// BN fold: y@W = x@(scale*W) + (shift@W)  => main never needs scale/shift.
// ---------------------------------------------------------------------------

#define VNODES 10
#define CH 128
#define ROWS_TOTAL 327680      // 64*512*10
#define G 4                    // batch items per main block
#define MROWS 40               // real rows per block
#define MT 3                   // 16-row m-tiles (48 rows; 40-47 garbage, masked)
#define SX 136                 // xT/qT row stride (bf16 elems), 272B: 2-way-free b128
#define SK 132                 // kT/vT/out row stride (f32), 528B: 16B-aligned

typedef __bf16 bf16x8 __attribute__((ext_vector_type(8)));
typedef float f32x4 __attribute__((ext_vector_type(4)));
typedef unsigned short u16x8 __attribute__((ext_vector_type(8)));

__device__ __forceinline__ float bf2f(unsigned short u) {
    return __uint_as_float(((unsigned)u) << 16);
}
__device__ __forceinline__ unsigned short f2bf(float f) {
    unsigned u = __float_as_uint(f);
    u += 0x7fffu + ((u >> 16) & 1u);   // RNE
    return (unsigned short)(u >> 16);
}

// ---------------------------------------------------------------------------
// BN statistics: per-channel sum / sumsq. 2048 blocks x 256 thr, 160 rows each.
// ---------------------------------------------------------------------------
__global__ __launch_bounds__(256) void stats_kernel(
        const float* __restrict__ x,
        float* __restrict__ ws_sum, float* __restrict__ ws_sq) {
    __shared__ float lsum[8][128];
    __shared__ float lsq[8][128];
    int t = threadIdx.x;
    int slot = t >> 5, g = t & 31;
    float s[4], q[4];
#pragma unroll
    for (int k = 0; k < 4; ++k) { s[k] = 0.f; q[k] = 0.f; }
    size_t base_row = (size_t)blockIdx.x * 160;
    for (int p = 0; p < 20; ++p) {
        size_t row = base_row + p * 8 + slot;
        f32x4 v = *(const f32x4*)(x + row * CH + g * 4);
#pragma unroll
        for (int k = 0; k < 4; ++k) {
            s[k] += v[k];
            q[k] = fmaf(v[k], v[k], q[k]);
        }
    }
#pragma unroll
    for (int k = 0; k < 4; ++k) { lsum[slot][g * 4 + k] = s[k]; lsq[slot][g * 4 + k] = q[k]; }
    __syncthreads();
    if (t < 128) {
        float ts = 0.f, tq = 0.f;
#pragma unroll
        for (int sl = 0; sl < 8; ++sl) { ts += lsum[sl][t]; tq += lsq[sl][t]; }
        atomicAdd(&ws_sum[t], ts);
        atomicAdd(&ws_sq[t], tq);
    }
}

// ---------------------------------------------------------------------------
// Weight prep (AFTER stats): BN-folded MFMA B-fragments + qkv bias vector.
// frag[nt][kt][lane][j] = scale[k]*W[k][nt*16+(lane&15)], k=kt*32+(lane>>4)*8+j
// bq[n] = sum_c shift[c]*W[c][n]
// ---------------------------------------------------------------------------
__global__ __launch_bounds__(256) void prep_kernel(
        const float* __restrict__ wqkv, const float* __restrict__ wout,
        const float* __restrict__ gamma, const float* __restrict__ beta,
        const float* __restrict__ stats,
        unsigned short* __restrict__ fq, unsigned short* __restrict__ fo,
        float* __restrict__ bq) {
    __shared__ float sh_s[128];
    if (blockIdx.x < 32) {
        int tid = blockIdx.x * 256 + threadIdx.x;
        if (tid < 24 * 4 * 64) {                    // w_qkv frags (BN-scaled)
            int l = tid & 63;
            int kt = (tid >> 6) & 3;
            int nt = tid >> 8;
            int quad = l >> 4, n = l & 15;
#pragma unroll
            for (int j = 0; j < 8; ++j) {
                int k = kt * 32 + quad * 8 + j;
                float mean = stats[k] * (1.0f / ROWS_TOTAL);
                float var = stats[128 + k] * (1.0f / ROWS_TOTAL) - mean * mean;
                float sc = gamma[k] * rsqrtf(var + 1e-5f);
                fq[tid * 8 + j] = f2bf(sc * wqkv[k * 384 + nt * 16 + n]);
            }
        } else if (tid < 24 * 4 * 64 + 8 * 4 * 64) { // w_out frags
            int u = tid - 24 * 4 * 64;
            int l = u & 63;
            int kt = (u >> 6) & 3;
            int nt = u >> 8;
            int quad = l >> 4, n = l & 15;
#pragma unroll
            for (int j = 0; j < 8; ++j) {
                int k = kt * 32 + quad * 8 + j;
                fo[u * 8 + j] = f2bf(wout[k * 128 + nt * 16 + n]);
            }
        }
    } else {                                        // block 32: qkv bias
        int t = threadIdx.x;
        if (t < 128) {
            float mean = stats[t] * (1.0f / ROWS_TOTAL);
            float var = stats[128 + t] * (1.0f / ROWS_TOTAL) - mean * mean;
            float sc = gamma[t] * rsqrtf(var + 1e-5f);
            sh_s[t] = beta[t] - mean * sc;
        }
        __syncthreads();
        for (int n = t; n < 384; n += 256) {
            float acc = 0.f;
#pragma unroll 8
            for (int c = 0; c < 128; ++c) acc = fmaf(sh_s[c], wqkv[c * 384 + n], acc);
            bq[n] = acc;
        }
    }
}

// ---------------------------------------------------------------------------
// Main fused kernel: 512 thr (8 waves), 8192 blocks, 40 rows (4 batch items).
// LDS ~69KB -> 2 blocks/CU (16 waves).
// ---------------------------------------------------------------------------
__global__ __launch_bounds__(512, 4) void main_kernel(
        const float* __restrict__ x,
        const float* __restrict__ maskp,
        const float* __restrict__ bq,
        const unsigned short* __restrict__ wqkv_f,
        const unsigned short* __restrict__ wout_f,
        const float* __restrict__ b_out,
        float* __restrict__ out) {
    __shared__ __align__(16) unsigned short xT[48 * SX];   // 13,056 B (x bf16; later attn-out)
    __shared__ __align__(16) unsigned short qT[40 * SX];   // 10,880 B (Q bf16)
    __shared__ __align__(16) float kT[40 * SK];            // 21,120 B (K fp32; later out fp32)
    __shared__ __align__(16) float vT[40 * SK];            // 21,120 B (V fp32)
    __shared__ float bq_s[384], bout_s[128], mask_s[VNODES * VNODES];

    int tid = threadIdx.x;
    int lane = tid & 63, w = tid >> 6;
    size_t row0 = (size_t)blockIdx.x * MROWS;

    // ---- phase 0: constants into LDS; zero xT pad rows ----
    if (tid < 384) bq_s[tid] = bq[tid];
    else bout_s[tid - 384] = b_out[tid - 384];
    if (tid < VNODES * VNODES) mask_s[tid] = maskp[tid];
    {   // zero garbage rows 40-47 of xT (finite values for MFMA)
        int r = 40 + (tid >> 6), c = (tid & 63) * 2;
        *(unsigned*)(xT + r * SX + c) = 0u;
    }

    // ---- phase 1: x (fp32) -> bf16 xT ----
    {
#pragma unroll
        for (int p = 0; p < 3; ++p) {
            int idx = p * 512 + tid;              // 1280 f32x4 total
            if (idx < 1280) {
                int r = idx >> 5, g = idx & 31;
                f32x4 v = *(const f32x4*)(x + (row0 + r) * CH + g * 4);
                unsigned short o0 = f2bf(v[0]), o1 = f2bf(v[1]);
                unsigned short o2 = f2bf(v[2]), o3 = f2bf(v[3]);
                unsigned two0 = (unsigned)o0 | ((unsigned)o1 << 16);
                unsigned two1 = (unsigned)o2 | ((unsigned)o3 << 16);
                *(unsigned*)(xT + r * SX + g * 4) = two0;
                *(unsigned*)(xT + r * SX + g * 4 + 2) = two1;
            }
        }
    }
    __syncthreads();

    // ---- phase 2: qkv = x @ W' + bq via MFMA; wave w: nt {w(Q), w+8(K), w+16(V)} ----
    {
        bf16x8 bf[3][4];
#pragma unroll
        for (int ni = 0; ni < 3; ++ni) {
            int nt = w + ni * 8;
#pragma unroll
            for (int kt = 0; kt < 4; ++kt)
                bf[ni][kt] = *(const bf16x8*)(wqkv_f + ((nt * 4 + kt) * 64 + lane) * 8);
        }
        int l15 = lane & 15, quad = lane >> 4;
        for (int mt = 0; mt < MT; ++mt) {
            bf16x8 a[4];
#pragma unroll
            for (int kt = 0; kt < 4; ++kt)
                a[kt] = *(const bf16x8*)(xT + (mt * 16 + l15) * SX + kt * 32 + quad * 8);
            f32x4 accq = {0.f,0.f,0.f,0.f}, acck = {0.f,0.f,0.f,0.f}, accv = {0.f,0.f,0.f,0.f};
#pragma unroll
            for (int kt = 0; kt < 4; ++kt) {
                accq = __builtin_amdgcn_mfma_f32_16x16x32_bf16(a[kt], bf[0][kt], accq, 0, 0, 0);
                acck = __builtin_amdgcn_mfma_f32_16x16x32_bf16(a[kt], bf[1][kt], acck, 0, 0, 0);
                accv = __builtin_amdgcn_mfma_f32_16x16x32_bf16(a[kt], bf[2][kt], accv, 0, 0, 0);
            }
            int col = w * 16 + l15;
            float bqq = bq_s[col], bqk = bq_s[128 + col], bqv = bq_s[256 + col];
#pragma unroll
            for (int i = 0; i < 4; ++i) {
                int rr = mt * 16 + quad * 4 + i;
                if (rr < MROWS) {
                    qT[rr * SX + col] = f2bf(accq[i] + bqq);
                    kT[rr * SK + col] = acck[i] + bqk;
                    vT[rr * SK + col] = accv[i] + bqv;
                }
            }
        }
    }
    __syncthreads();

    // ---- phase 2b: masked attention, fp32; 320 tasks on threads 0-319 ----
    if (tid < G * 8 * VNODES) {
        int h = tid / (G * VNODES);
        int rem = tid - h * (G * VNODES);
        int b = rem / VNODES;
        int i = rem - b * VNODES;
        int rowi = b * VNODES + i;
        const unsigned short* qp = qT + rowi * SX + h * 16;
        float qv[16];
#pragma unroll
        for (int d2 = 0; d2 < 8; ++d2) {
            unsigned wd = *(const unsigned*)(qp + d2 * 2);
            qv[d2 * 2]     = __uint_as_float(wd << 16);
            qv[d2 * 2 + 1] = __uint_as_float(wd & 0xffff0000u);
        }
        float p[VNODES];
        float mx = -1e30f;
#pragma unroll
        for (int j = 0; j < VNODES; ++j) {
            const float* kp = kT + (b * VNODES + j) * SK + h * 16;
            f32x4 k0 = *(const f32x4*)kp,     k1 = *(const f32x4*)(kp + 4);
            f32x4 k2 = *(const f32x4*)(kp + 8), k3 = *(const f32x4*)(kp + 12);
            float dot = 0.f;
#pragma unroll
            for (int d = 0; d < 4; ++d) {
                dot = fmaf(qv[d], k0[d], dot);
                dot = fmaf(qv[4 + d], k1[d], dot);
                dot = fmaf(qv[8 + d], k2[d], dot);
                dot = fmaf(qv[12 + d], k3[d], dot);
            }
            p[j] = dot * 0.25f * mask_s[i * VNODES + j];   // softmax over ALL 10
            mx = fmaxf(mx, p[j]);
        }
        float s = 0.f;
#pragma unroll
        for (int j = 0; j < VNODES; ++j) { p[j] = __expf(p[j] - mx); s += p[j]; }
        float inv = 1.0f / s;
        float o[16];
#pragma unroll
        for (int d = 0; d < 16; ++d) o[d] = 0.f;
#pragma unroll
        for (int j = 0; j < VNODES; ++j) {
            const float* vp = vT + (b * VNODES + j) * SK + h * 16;
            f32x4 v0 = *(const f32x4*)vp,     v1 = *(const f32x4*)(vp + 4);
            f32x4 v2 = *(const f32x4*)(vp + 8), v3 = *(const f32x4*)(vp + 12);
#pragma unroll
            for (int d = 0; d < 4; ++d) {
                o[d]      = fmaf(p[j], v0[d], o[d]);
                o[4 + d]  = fmaf(p[j], v1[d], o[4 + d]);
                o[8 + d]  = fmaf(p[j], v2[d], o[8 + d]);
                o[12 + d] = fmaf(p[j], v3[d], o[12 + d]);
            }
        }
#pragma unroll
        for (int d2 = 0; d2 < 8; ++d2) {
            unsigned ow = (unsigned)f2bf(o[d2 * 2] * inv)
                        | ((unsigned)f2bf(o[d2 * 2 + 1] * inv) << 16);
            *(unsigned*)(xT + rowi * SX + h * 16 + d2 * 2) = ow;  // xT rows 0-39 = attn out
        }
    }
    __syncthreads();

    // ---- phase 3: final = attn @ w_out + b_out; fp32 tile into kT ----
    {
        bf16x8 bfw[4];
#pragma unroll
        for (int kt = 0; kt < 4; ++kt)
            bfw[kt] = *(const bf16x8*)(wout_f + ((w * 4 + kt) * 64 + lane) * 8);
        int l15 = lane & 15, quad = lane >> 4;
        int col = w * 16 + l15;
        float bias = bout_s[col];
        for (int mt = 0; mt < MT; ++mt) {
            f32x4 acc = {0.f, 0.f, 0.f, 0.f};
#pragma unroll
            for (int kt = 0; kt < 4; ++kt) {
                bf16x8 a = *(const bf16x8*)(xT + (mt * 16 + l15) * SX + kt * 32 + quad * 8);
                acc = __builtin_amdgcn_mfma_f32_16x16x32_bf16(a, bfw[kt], acc, 0, 0, 0);
            }
#pragma unroll
            for (int i = 0; i < 4; ++i) {
                int rr = mt * 16 + quad * 4 + i;
                if (rr < MROWS) kT[rr * SK + col] = acc[i] + bias;   // kT now = out tile
            }
        }
    }
    __syncthreads();

    // ---- phase 4: coalesced fp32 store ----
    {
#pragma unroll
        for (int p = 0; p < 3; ++p) {
            int idx = p * 512 + tid;              // 1280 f32x4
            if (idx < 1280) {
                int r = idx >> 5, g = idx & 31;
                *(f32x4*)(out + (row0 + r) * CH + g * 4) = *(const f32x4*)(kT + r * SK + g * 4);
            }
        }
    }
}

extern "C" void kernel_launch(void* const* d_in, const int* in_sizes, int n_in,
                              void* d_out, int out_size, void* d_ws, size_t ws_size,
                              hipStream_t stream) {
    const float* x     = (const float*)d_in[0];
    const float* gamma = (const float*)d_in[1];
    const float* beta  = (const float*)d_in[2];
    const float* wqkv  = (const float*)d_in[3];
    const float* wout  = (const float*)d_in[4];
    const float* bout  = (const float*)d_in[5];
    const float* maskp = (const float*)d_in[6];
    float* out = (float*)d_out;

    char* ws = (char*)d_ws;
    float* ws_stats = (float*)ws;                          // 256 f32 (sum | sumsq)
    float* bq = (float*)(ws + 1024);                       // 384 f32 qkv bias
    unsigned short* fq = (unsigned short*)(ws + 4096);     // 49152 bf16 qkv frags
    unsigned short* fo = (unsigned short*)(ws + 4096 + 98304); // 16384 bf16 out frags

    hipMemsetAsync(ws, 0, 1024, stream);
    stats_kernel<<<2048, 256, 0, stream>>>(x, ws_stats, ws_stats + 128);
    prep_kernel<<<33, 256, 0, stream>>>(wqkv, wout, gamma, beta, ws_stats, fq, fo, bq);
    main_kernel<<<8192, 512, 0, stream>>>(x, maskp, bq, fq, fo, bout, out);
}